// Round 6
// baseline (892.755 us; speedup 1.0000x reference)
//
#include <hip/hip_runtime.h>

#define N_NODES 100000
#define E_EDGES 1600000
#define IN_CH   512
#define HID     256
#define OUT_CH  32
#define K_STEPS 10
#define EPAD    (E_EDGES + 8 * N_NODES)   // worst-case pad-to-8 CSR length

typedef unsigned short u16;
typedef unsigned int   u32;

typedef __attribute__((ext_vector_type(8))) short bf16x8;
typedef __attribute__((ext_vector_type(4))) float f32x4;

__device__ __forceinline__ float b2f(u16 u) {
    union { u32 i; float f; } x; x.i = ((u32)u) << 16; return x.f;
}
__device__ __forceinline__ u16 f2b(float f) {
    union { float f; u32 u; } x; x.f = f;
    u32 r = x.u + 0x7fffu + ((x.u >> 16) & 1u);
    return (u16)(r >> 16);
}
__device__ __forceinline__ float hi_f(u32 v) {
    union { u32 u; float f; } x; x.u = v & 0xffff0000u; return x.f;
}
__device__ __forceinline__ float lo_f(u32 v) {
    union { u32 u; float f; } x; x.u = v << 16; return x.f;
}

// async global->LDS, 16B per lane. LDS dest is wave-uniform base + lane*16.
__device__ __forceinline__ void load_lds16(const void* g, void* l) {
    __builtin_amdgcn_global_load_lds(
        (const __attribute__((address_space(1))) unsigned int*)g,
        (__attribute__((address_space(3))) unsigned int*)l,
        16, 0, 0);
}

// ---------------- casts ----------------

__global__ __launch_bounds__(256) void k_cast(const float* __restrict__ in, u16* __restrict__ out, int n4) {
    int i = blockIdx.x * 256 + threadIdx.x;
    if (i < n4) {
        float4 f = ((const float4*)in)[i];
        ushort4 u;
        u.x = f2b(f.x); u.y = f2b(f.y); u.z = f2b(f.z); u.w = f2b(f.w);
        ((ushort4*)out)[i] = u;
    }
}

// ---------------- preprocessing: degree, dinv, padded scan, CSR fill ----------------

__global__ __launch_bounds__(256) void k_count(const int* __restrict__ col, int* __restrict__ cnt) {
    int i = blockIdx.x * 256 + threadIdx.x;
    if (i < E_EDGES) atomicAdd(&cnt[col[i]], 1);
}

__global__ __launch_bounds__(256) void k_dinv(const int* __restrict__ cnt, float* __restrict__ dinv) {
    int i = blockIdx.x * 256 + threadIdx.x;
    if (i < N_NODES) dinv[i] = rsqrtf((float)(cnt[i] + 1));  // +1 self-loop
}

__device__ __forceinline__ int pad8(int v) { return (v + 7) & ~7; }

__global__ __launch_bounds__(256) void k_blocksum(const int* __restrict__ cnt, int* __restrict__ bs) {
    int b = blockIdx.x, t = threadIdx.x;
    int idx = b * 1024 + t * 4;
    int s = 0;
    #pragma unroll
    for (int j = 0; j < 4; ++j) if (idx + j < N_NODES) s += pad8(cnt[idx + j]);
    #pragma unroll
    for (int d = 32; d > 0; d >>= 1) s += __shfl_down(s, d, 64);
    __shared__ int smem[4];
    int lane = t & 63, w = t >> 6;
    if (lane == 0) smem[w] = s;
    __syncthreads();
    if (t == 0) bs[b] = smem[0] + smem[1] + smem[2] + smem[3];
}

__global__ void k_scanblocks(const int* __restrict__ bs, int* __restrict__ bo, int nb) {
    int t = threadIdx.x;  // 128 threads, nb <= 128
    int v = (t < nb) ? bs[t] : 0;
    int incl = v;
    int lane = t & 63, w = t >> 6;
    #pragma unroll
    for (int d = 1; d < 64; d <<= 1) { int tt = __shfl_up(incl, d, 64); if (lane >= d) incl += tt; }
    __shared__ int wsum[2];
    if (lane == 63) wsum[w] = incl;
    __syncthreads();
    int add = (w == 1) ? wsum[0] : 0;
    if (t < nb) bo[t] = add + incl - v;  // exclusive
}

__global__ __launch_bounds__(256) void k_scanwithin(const int* __restrict__ cnt, const int* __restrict__ bo,
                                                    int* __restrict__ off) {
    int b = blockIdx.x, t = threadIdx.x;
    int idx = b * 1024 + t * 4;
    int v[4]; int s = 0;
    #pragma unroll
    for (int j = 0; j < 4; ++j) { v[j] = (idx + j < N_NODES) ? pad8(cnt[idx + j]) : 0; s += v[j]; }
    int incl = s;
    int lane = t & 63, w = t >> 6;
    #pragma unroll
    for (int d = 1; d < 64; d <<= 1) { int tt = __shfl_up(incl, d, 64); if (lane >= d) incl += tt; }
    __shared__ int wsum[4];
    if (lane == 63) wsum[w] = incl;
    __syncthreads();
    int woff = 0;
    #pragma unroll
    for (int k = 0; k < 4; ++k) if (k < w) woff += wsum[k];
    int run = bo[b] + woff + incl - s;
    #pragma unroll
    for (int j = 0; j < 4; ++j) { if (idx + j < N_NODES) off[idx + j] = run; run += v[j]; }
}

__global__ __launch_bounds__(256) void k_total(const int* __restrict__ bo, const int* __restrict__ bs,
                                               int* __restrict__ off, int nb) {
    off[N_NODES] = bo[nb - 1] + bs[nb - 1];
}

// prefill padded CSR with the dummy node index (p[N] == 0 always)
__global__ __launch_bounds__(256) void k_filldummy(int* __restrict__ csr_row) {
    int i = blockIdx.x * 256 + threadIdx.x;
    if (i < EPAD) csr_row[i] = N_NODES;
}

__global__ __launch_bounds__(256) void k_fill(const int* __restrict__ row, const int* __restrict__ col,
                                              const int* __restrict__ off, int* __restrict__ cursor,
                                              int* __restrict__ csr_row) {
    int i = blockIdx.x * 256 + threadIdx.x;
    if (i < E_EDGES) {
        int c = col[i];
        int pos = off[c] + atomicAdd(&cursor[c], 1);
        csr_row[pos] = row[i];
    }
}

// ---------------- bf16 MFMA GEMM: 128x128 tile, 4 waves, 64x64/wave ----------------
// Out[m][n] = relu(A[m][:] . Bt[n][:] + bias[n]) (+ resid if RESID), Out bf16 ld=256

template<int KDIM, bool RESID>
__global__ __launch_bounds__(256) void gemm_mfma(const u16* __restrict__ A,
                                                 const u16* __restrict__ Bt,
                                                 const float* __restrict__ bias,
                                                 const u16* __restrict__ resid,
                                                 u16* __restrict__ Out,
                                                 int M) {
    __shared__ u16 As[128 * 32];
    __shared__ u16 Bs[128 * 32];
    const int t = threadIdx.x;
    const int lane = t & 63, w = t >> 6;
    const int row0 = blockIdx.x * 128, col0 = blockIdx.y * 128;

    f32x4 acc[4][4] = {};
    const int rr = lane >> 2, cc = lane & 3;
    const int wr = (w >> 1) * 64, wc = (w & 1) * 64;
    const int fr = lane & 15, quad = lane >> 4;

    for (int k0 = 0; k0 < KDIM; k0 += 32) {
        #pragma unroll
        for (int rep = 0; rep < 2; ++rep) {
            int ii = w * 2 + rep;
            int gr = row0 + ii * 16 + rr;
            if (gr > M - 1) gr = M - 1;           // clamp: garbage rows never stored
            load_lds16(A + (size_t)gr * KDIM + k0 + cc * 8, &As[ii * 512]);
        }
        #pragma unroll
        for (int rep = 0; rep < 2; ++rep) {
            int ii = w * 2 + rep;
            int gc = col0 + ii * 16 + rr;
            load_lds16(Bt + (size_t)gc * KDIM + k0 + cc * 8, &Bs[ii * 512]);
        }
        __syncthreads();

        bf16x8 af[4], bfr[4];
        #pragma unroll
        for (int ti = 0; ti < 4; ++ti)
            af[ti] = *(const bf16x8*)&As[(wr + ti * 16 + fr) * 32 + quad * 8];
        #pragma unroll
        for (int tj = 0; tj < 4; ++tj)
            bfr[tj] = *(const bf16x8*)&Bs[(wc + tj * 16 + fr) * 32 + quad * 8];
        #pragma unroll
        for (int ti = 0; ti < 4; ++ti)
            #pragma unroll
            for (int tj = 0; tj < 4; ++tj)
                acc[ti][tj] = __builtin_amdgcn_mfma_f32_16x16x32_bf16(af[ti], bfr[tj], acc[ti][tj], 0, 0, 0);
        __syncthreads();
    }

    #pragma unroll
    for (int tj = 0; tj < 4; ++tj) {
        int col = col0 + wc + tj * 16 + fr;
        float bv = bias[col];
        #pragma unroll
        for (int ti = 0; ti < 4; ++ti) {
            #pragma unroll
            for (int r = 0; r < 4; ++r) {
                int grow = row0 + wr + ti * 16 + quad * 4 + r;
                if (grow < M) {
                    float v = fmaxf(acc[ti][tj][r] + bv, 0.f);
                    if constexpr (RESID) v += b2f(resid[(size_t)grow * HID + col]);
                    Out[(size_t)grow * HID + col] = f2b(v);
                }
            }
        }
    }
}

// GEMM3: h0[m][c] = xres[m][:] . W2[c][:] + b2[c]; also p0 = bf16(dinv .* h0)
__global__ __launch_bounds__(256) void gemm_out(const u16* __restrict__ xres, const float* __restrict__ W2,
                                                const float* __restrict__ b2, const float* __restrict__ dinv,
                                                float* __restrict__ h0, u16* __restrict__ p0, int M) {
    constexpr int BM = 128, BK = 16, KDIM = HID;
    __shared__ float As[BK][BM + 4];
    __shared__ float Bs[BK][OUT_CH + 4];
    int t = threadIdx.x;
    int row0 = blockIdx.x * BM;

    float acc[4][4];
    #pragma unroll
    for (int i = 0; i < 4; ++i)
        #pragma unroll
        for (int j = 0; j < 4; ++j) acc[i][j] = 0.f;

    for (int k0 = 0; k0 < KDIM; k0 += BK) {
        #pragma unroll
        for (int rep = 0; rep < 2; ++rep) {
            int idx = rep * 256 + t;
            int r = idx >> 2, ch = idx & 3;
            int gr = row0 + r;
            float v0, v1, v2, v3;
            if (gr < M) {
                ushort4 u = *(const ushort4*)&xres[(size_t)gr * KDIM + k0 + ch * 4];
                v0 = b2f(u.x); v1 = b2f(u.y); v2 = b2f(u.z); v3 = b2f(u.w);
            } else { v0 = v1 = v2 = v3 = 0.f; }
            As[ch * 4 + 0][r] = v0; As[ch * 4 + 1][r] = v1;
            As[ch * 4 + 2][r] = v2; As[ch * 4 + 3][r] = v3;
        }
        if (t < 128) {
            int nn = t >> 2, ch = t & 3;
            float4 f = *(const float4*)&W2[(size_t)nn * KDIM + k0 + ch * 4];
            Bs[ch * 4 + 0][nn] = f.x; Bs[ch * 4 + 1][nn] = f.y;
            Bs[ch * 4 + 2][nn] = f.z; Bs[ch * 4 + 3][nn] = f.w;
        }
        __syncthreads();
        int ty = t >> 3, tx = t & 7;
        #pragma unroll
        for (int kk = 0; kk < BK; ++kk) {
            float a[4], wv[4];
            *(float4*)&a[0] = *(const float4*)&As[kk][ty * 4];
            *(float4*)&wv[0] = *(const float4*)&Bs[kk][tx * 4];
            #pragma unroll
            for (int i = 0; i < 4; ++i)
                #pragma unroll
                for (int j = 0; j < 4; ++j) acc[i][j] = fmaf(a[i], wv[j], acc[i][j]);
        }
        __syncthreads();
    }
    int ty = t >> 3, tx = t & 7;
    #pragma unroll
    for (int i = 0; i < 4; ++i) {
        int gr = row0 + ty * 4 + i;
        if (gr < M) {
            float dv = dinv[gr];
            float4 v;
            v.x = acc[i][0] + b2[tx * 4 + 0];
            v.y = acc[i][1] + b2[tx * 4 + 1];
            v.z = acc[i][2] + b2[tx * 4 + 2];
            v.w = acc[i][3] + b2[tx * 4 + 3];
            *(float4*)&h0[(size_t)gr * OUT_CH + tx * 4] = v;
            ushort4 u;
            u.x = f2b(dv * v.x); u.y = f2b(dv * v.y);
            u.z = f2b(dv * v.z); u.w = f2b(dv * v.w);
            *(ushort4*)&p0[(size_t)gr * OUT_CH + tx * 4] = u;
        }
    }
}

// ---------------- propagation: 8 lanes/node, pad-8 CSR, broadcast idx loads ----------------
// p layout: u32[node][16]; lane l of its 8-lane group handles u32 pair (2l,2l+1)
// = channels 4l..4l+3. Row N_NODES is all-zero (dummy for padding).

__global__ __launch_bounds__(256) void k_prop(const u32* __restrict__ pin, u32* __restrict__ pout,
                                              float* __restrict__ hout, const float* __restrict__ h0,
                                              const int* __restrict__ off, const int* __restrict__ csr_row,
                                              const float* __restrict__ dinv, int last) {
    int t = threadIdx.x;
    int gw = blockIdx.x * 32 + (t >> 3);     // node (grid = N/32 blocks, N%32==0)
    int l = t & 7;                           // channel quad
    int s = off[gw], e = off[gw + 1];        // (e-s) % 8 == 0 by construction
    float dv = dinv[gw];
    uint2 selfp = *(const uint2*)&pin[(size_t)gw * 16 + 2 * l];
    float4 h0v = ((const float4*)h0)[(size_t)gw * 8 + l];

    float a0 = 0.f, a1 = 0.f, a2 = 0.f, a3 = 0.f;
    for (int base = s; base < e; base += 8) {
        int r[8];
        #pragma unroll
        for (int i = 0; i < 8; ++i) r[i] = csr_row[base + i];   // same addr across group: broadcast, L1-hit
        uint2 v[8];
        #pragma unroll
        for (int i = 0; i < 8; ++i) v[i] = *(const uint2*)&pin[(size_t)r[i] * 16 + 2 * l];  // 8 gathers in flight
        #pragma unroll
        for (int i = 0; i < 8; ++i) {
            a0 += lo_f(v[i].x); a1 += hi_f(v[i].x);
            a2 += lo_f(v[i].y); a3 += hi_f(v[i].y);
        }
    }
    a0 += lo_f(selfp.x); a1 += hi_f(selfp.x);
    a2 += lo_f(selfp.y); a3 += hi_f(selfp.y);
    float h0c = 0.9f * dv * a0 + 0.1f * h0v.x;
    float h1c = 0.9f * dv * a1 + 0.1f * h0v.y;
    float h2c = 0.9f * dv * a2 + 0.1f * h0v.z;
    float h3c = 0.9f * dv * a3 + 0.1f * h0v.w;
    if (last) {
        ((float4*)hout)[(size_t)gw * 8 + l] = make_float4(h0c, h1c, h2c, h3c);
    } else {
        uint2 o;
        o.x = (u32)f2b(dv * h0c) | ((u32)f2b(dv * h1c) << 16);
        o.y = (u32)f2b(dv * h2c) | ((u32)f2b(dv * h3c) << 16);
        *(uint2*)&pout[(size_t)gw * 16 + 2 * l] = o;
    }
}

// ---------------- launch ----------------

extern "C" void kernel_launch(void* const* d_in, const int* in_sizes, int n_in,
                              void* d_out, int out_size, void* d_ws, size_t ws_size,
                              hipStream_t stream) {
    const float* x  = (const float*)d_in[0];
    const int*   ei = (const int*)d_in[1];      // [2][E]
    const float* W1 = (const float*)d_in[2];
    const float* b1 = (const float*)d_in[3];
    const float* Wr = (const float*)d_in[4];
    const float* br = (const float*)d_in[5];
    const float* W2 = (const float*)d_in[6];
    const float* b2 = (const float*)d_in[7];
    float* out = (float*)d_out;

    char* ws = (char*)d_ws;
    size_t off_b = 0;
    auto take = [&](size_t bytes) {
        void* p = ws + off_b;
        off_b += (bytes + 255) & ~(size_t)255;
        return p;
    };

    float* h0      = (float*)take((size_t)N_NODES * OUT_CH * 4);
    u16*   pA      = (u16*)  take((size_t)(N_NODES + 1) * OUT_CH * 2);
    u16*   pB      = (u16*)  take((size_t)(N_NODES + 1) * OUT_CH * 2);
    int*   csr_row = (int*)  take((size_t)EPAD * 4);
    float* dinv    = (float*)take((size_t)N_NODES * 4);
    int*   cnt     = (int*)  take((size_t)N_NODES * 4);
    int*   offs    = (int*)  take((size_t)(N_NODES + 1) * 4);
    int*   cursor  = (int*)  take((size_t)N_NODES * 4);
    int*   bs      = (int*)  take(1024);
    int*   bo      = (int*)  take(1024);
    u16*   h1      = (u16*)  take((size_t)N_NODES * HID * 2);
    u16*   xres    = (u16*)  take((size_t)N_NODES * HID * 2);
    u16*   W1b     = (u16*)  take((size_t)HID * IN_CH * 2);
    u16*   Wrb     = (u16*)  take((size_t)HID * HID * 2);
    u16*   xb      = (u16*)  take((size_t)N_NODES * IN_CH * 2);

    const int* e_row = ei;
    const int* e_col = ei + E_EDGES;

    // 1) casts
    k_cast<<<(N_NODES * IN_CH / 4 + 255) / 256, 256, 0, stream>>>(x, xb, N_NODES * IN_CH / 4);
    k_cast<<<(HID * IN_CH / 4 + 255) / 256, 256, 0, stream>>>(W1, W1b, HID * IN_CH / 4);
    k_cast<<<(HID * HID / 4 + 255) / 256, 256, 0, stream>>>(Wr, Wrb, HID * HID / 4);

    // 2) GEMM1: h1 = relu(x @ W1^T + b1)  (bf16 A via global_load_lds — async DMA)
    dim3 g12((N_NODES + 127) / 128, HID / 128);
    gemm_mfma<IN_CH, false><<<g12, 256, 0, stream>>>(xb, W1b, b1, nullptr, h1, N_NODES);

    // 3) preprocessing (pad-8 CSR)
    hipMemsetAsync(cnt, 0, (size_t)N_NODES * 4, stream);
    hipMemsetAsync(cursor, 0, (size_t)N_NODES * 4, stream);
    hipMemsetAsync(pA + (size_t)N_NODES * OUT_CH, 0, OUT_CH * 2, stream);  // zero dummy row
    hipMemsetAsync(pB + (size_t)N_NODES * OUT_CH, 0, OUT_CH * 2, stream);
    const int NB = (N_NODES + 1023) / 1024;  // 98
    k_count<<<(E_EDGES + 255) / 256, 256, 0, stream>>>(e_col, cnt);
    k_dinv<<<(N_NODES + 255) / 256, 256, 0, stream>>>(cnt, dinv);
    k_blocksum<<<NB, 256, 0, stream>>>(cnt, bs);
    k_scanblocks<<<1, 128, 0, stream>>>(bs, bo, NB);
    k_scanwithin<<<NB, 256, 0, stream>>>(cnt, bo, offs);
    k_total<<<1, 1, 0, stream>>>(bo, bs, offs, NB);
    k_filldummy<<<(EPAD + 255) / 256, 256, 0, stream>>>(csr_row);
    k_fill<<<(E_EDGES + 255) / 256, 256, 0, stream>>>(e_row, e_col, offs, cursor, csr_row);

    // 4) GEMM2: xres = h1 + relu(h1 @ Wr^T + br)
    gemm_mfma<HID, true><<<g12, 256, 0, stream>>>(h1, Wrb, br, h1, xres, N_NODES);

    // 5) GEMM3: h0 = xres @ W2^T + b2 ; p0 = bf16(dinv .* h0) -> pA
    gemm_out<<<(N_NODES + 127) / 128, 256, 0, stream>>>(xres, W2, b2, dinv, h0, pA, N_NODES);

    // 6) propagation: K steps on packed bf16 p, final step writes fp32 h to out
    const u32* pin = (const u32*)pA;
    for (int s = 0; s < K_STEPS; ++s) {
        int last = (s == K_STEPS - 1);
        u32* pout = (u32*)((s & 1) ? pA : pB);
        k_prop<<<N_NODES / 32, 256, 0, stream>>>(pin, pout, out, h0, offs, csr_row, dinv, last);
        pin = pout;
    }
}